// Round 1
// baseline (265.599 us; speedup 1.0000x reference)
//
#include <hip/hip_runtime.h>

// bf16 MFMA fragment types (per guide §3, compile-verified pattern)
typedef short bf16x8 __attribute__((ext_vector_type(8)));
typedef float f32x4  __attribute__((ext_vector_type(4)));

#define LDP 72  // padded bf16 LDS row (64 + 8) to spread banks on ds_read_b128

__device__ __forceinline__ unsigned short f2bf(float f) {
    union { float f; unsigned int u; } v; v.f = f;
    unsigned int r = v.u + 0x7fffu + ((v.u >> 16) & 1u);  // RNE, inputs never NaN
    return (unsigned short)(r >> 16);
}

// ---------------------------------------------------------------------------
// prep: per (b, fixedIdx) block: slab[k][c] = src[b, ...], compute
//   Q[n=bx*64+c][j] = sum_k slab[k][c]*wq[k][j] + bq[j]   -> Qg  [b][4096][64] bf16
//   V[n][j]         = sum_k slab[k][c]*wv[k][j] + bv[j]   -> Vtg [b][64][4096] bf16 (transposed)
// height stage: bx=w, k=h (sK=4096,sF=64); width stage: bx=h, k=w (sK=64,sF=4096)
// If x1out != null (height stage) also copy src slab into x1 (same layout).
// ---------------------------------------------------------------------------
__global__ __launch_bounds__(256) void prep_kernel(
    const float* __restrict__ src,
    const float* __restrict__ wq, const float* __restrict__ bq,
    const float* __restrict__ wv, const float* __restrict__ bv,
    unsigned short* __restrict__ Qg, unsigned short* __restrict__ Vtg,
    float* __restrict__ x1out, int sK, int sF)
{
    __shared__ float slab[64][65];
    __shared__ float wqs[4096];
    __shared__ float wvs[4096];

    const int t  = threadIdx.x;
    const int bx = blockIdx.x, b = blockIdx.y;

    {   // stage weights (flat copy, coalesced float4)
        const float4* wq4 = (const float4*)wq;
        const float4* wv4 = (const float4*)wv;
        float4* q4 = (float4*)wqs; float4* v4 = (float4*)wvs;
        #pragma unroll
        for (int i = 0; i < 4; ++i) {
            q4[i*256 + t] = wq4[i*256 + t];
            v4[i*256 + t] = wv4[i*256 + t];
        }
    }
    {   // stage slab: thread t loads row k=t>>2, 16 floats at c0=(t&3)*16
        const int k = t >> 2, c0 = (t & 3) << 4;
        const size_t sb = (size_t)b*262144 + (size_t)k*sK + (size_t)bx*sF + c0;
        #pragma unroll
        for (int i = 0; i < 4; ++i) {
            float4 v = *(const float4*)&src[sb + i*4];
            *(float4*)&slab[k][c0 + i*4] = v;
            if (x1out) *(float4*)&x1out[sb + i*4] = v;
        }
    }
    __syncthreads();

    // compute: thread (c = t&63, jg = t>>6) produces j = jg*16..+15 for Q and V
    const int c = t & 63, jg = t >> 6;
    float qa[16], va[16];
    #pragma unroll
    for (int jj = 0; jj < 16; ++jj) { qa[jj] = bq[jg*16+jj]; va[jj] = bv[jg*16+jj]; }
    for (int k = 0; k < 64; ++k) {
        const float xv = slab[k][c];                 // conflict-free (2-way)
        const float* wqr = &wqs[k*64 + jg*16];       // wave-uniform -> broadcast
        const float* wvr = &wvs[k*64 + jg*16];
        #pragma unroll
        for (int jj = 0; jj < 16; ++jj) {
            qa[jj] += xv * wqr[jj];
            va[jj] += xv * wvr[jj];
        }
    }
    const int token = bx*64 + c;
    union { unsigned short s[16]; uint4 v[2]; } qp, vp;
    #pragma unroll
    for (int jj = 0; jj < 16; ++jj) { qp.s[jj] = f2bf(qa[jj]); vp.s[jj] = f2bf(va[jj]); }
    const size_t qoff = ((size_t)b*4096 + token)*64 + jg*16;
    *(uint4*)&Qg[qoff]     = qp.v[0];
    *(uint4*)&Qg[qoff + 8] = qp.v[1];
    #pragma unroll
    for (int jj = 0; jj < 16; ++jj)
        Vtg[((size_t)b*64 + jg*16 + jj)*4096 + token] = vp.s[jj];
}

// ---------------------------------------------------------------------------
// attn: Y[n][d] = sum_m sigmoid(Q[n]·Q[m]/8) * V[m][d], fused (no S matrix in HBM).
// 64-query tile per block, 64-key inner blocks, key-range split over gridDim.z=2.
// 4 waves in 2x2 over the 64x64 S tile / 64x64 Y tile. MFMA 16x16x32 bf16.
// axis 0 (height): dst=x1,  token n=(w,c): atomicAdd x1[b][d][mb][c&] += g*y
// axis 1 (width):  dst=out, token n=(h,c): atomicAdd out[b][mb][d][c&] += g*p*y
// ---------------------------------------------------------------------------
__global__ __launch_bounds__(256) void attn_kernel(
    const unsigned short* __restrict__ Qg,
    const unsigned short* __restrict__ Vtg,
    const float* __restrict__ gate,
    float* __restrict__ dst,
    const float* __restrict__ p,
    int axis)
{
    __shared__ unsigned short Qs [64][LDP];
    __shared__ unsigned short Ksh[64][LDP];
    __shared__ unsigned short Vts[64][LDP];
    __shared__ unsigned short Ss [64][LDP];

    const int t = threadIdx.x;
    const int mb = blockIdx.x, b = blockIdx.y, ksplit = blockIdx.z;
    const int lane = t & 63, wid = t >> 6;
    const int wm = wid & 1, wn = wid >> 1;
    const int quad = lane >> 4, l16 = lane & 15;

    const unsigned short* Qbase = Qg  + (size_t)b*262144;
    const unsigned short* Vbase = Vtg + (size_t)b*262144;

    const int lrow = t >> 2, loff = (t & 3) << 4;

    {   // Q tile: rows mb*64 + lrow (row-major bf16, 128B rows -> coalesced)
        const uint4* g = (const uint4*)(Qbase + (size_t)(mb*64 + lrow)*64 + loff);
        uint4 a0 = g[0], a1 = g[1];
        *(uint4*)&Qs[lrow][loff]     = a0;
        *(uint4*)&Qs[lrow][loff + 8] = a1;
    }
    __syncthreads();

    // hoist loop-invariant Q A-frags: A[m=l16][k=quad*8+j]
    bf16x8 qa[2][2];
    #pragma unroll
    for (int ti = 0; ti < 2; ++ti)
        #pragma unroll
        for (int s = 0; s < 2; ++s)
            qa[ti][s] = *(const bf16x8*)&Qs[wm*32 + ti*16 + l16][s*32 + quad*8];

    f32x4 y[2][2];
    #pragma unroll
    for (int ti = 0; ti < 2; ++ti)
        #pragma unroll
        for (int tj = 0; tj < 2; ++tj)
            y[ti][tj] = (f32x4){0.f, 0.f, 0.f, 0.f};

    for (int kb = 0; kb < 32; ++kb) {
        const int key0 = ksplit*2048 + kb*64;
        {   // stage K tile (= Q rows) and Vt tile
            const uint4* gk = (const uint4*)(Qbase + (size_t)(key0 + lrow)*64 + loff);
            uint4 k0 = gk[0], k1 = gk[1];
            const uint4* gv = (const uint4*)(Vbase + (size_t)lrow*4096 + key0 + loff);
            uint4 v0 = gv[0], v1 = gv[1];
            *(uint4*)&Ksh[lrow][loff]     = k0;
            *(uint4*)&Ksh[lrow][loff + 8] = k1;
            *(uint4*)&Vts[lrow][loff]     = v0;
            *(uint4*)&Vts[lrow][loff + 8] = v1;
        }
        __syncthreads();

        // S = Q Kt: A=Q[m][k], B[k][n]=K[n][k] -> B-frag reads K rows contiguously
        f32x4 sc[2][2];
        #pragma unroll
        for (int ti = 0; ti < 2; ++ti)
            #pragma unroll
            for (int tj = 0; tj < 2; ++tj)
                sc[ti][tj] = (f32x4){0.f, 0.f, 0.f, 0.f};
        #pragma unroll
        for (int s = 0; s < 2; ++s) {
            bf16x8 b0 = *(const bf16x8*)&Ksh[wn*32 +      l16][s*32 + quad*8];
            bf16x8 b1 = *(const bf16x8*)&Ksh[wn*32 + 16 + l16][s*32 + quad*8];
            sc[0][0] = __builtin_amdgcn_mfma_f32_16x16x32_bf16(qa[0][s], b0, sc[0][0], 0,0,0);
            sc[0][1] = __builtin_amdgcn_mfma_f32_16x16x32_bf16(qa[0][s], b1, sc[0][1], 0,0,0);
            sc[1][0] = __builtin_amdgcn_mfma_f32_16x16x32_bf16(qa[1][s], b0, sc[1][0], 0,0,0);
            sc[1][1] = __builtin_amdgcn_mfma_f32_16x16x32_bf16(qa[1][s], b1, sc[1][1], 0,0,0);
        }
        // sigmoid(x/8), C-layout (row=quad*4+r, col=l16) -> bf16 S in LDS (A-layout source)
        #pragma unroll
        for (int ti = 0; ti < 2; ++ti)
            #pragma unroll
            for (int tj = 0; tj < 2; ++tj)
                #pragma unroll
                for (int r = 0; r < 4; ++r) {
                    float sg = 1.0f / (1.0f + __expf(-0.125f * sc[ti][tj][r]));
                    Ss[wm*32 + ti*16 + quad*4 + r][wn*32 + tj*16 + l16] = f2bf(sg);
                }
        __syncthreads();

        // Y += S V: A=S[m][key], B[key][d]=Vt[d][key] rows contiguous
        #pragma unroll
        for (int s = 0; s < 2; ++s) {
            bf16x8 a0 = *(const bf16x8*)&Ss [wm*32 +      l16][s*32 + quad*8];
            bf16x8 a1 = *(const bf16x8*)&Ss [wm*32 + 16 + l16][s*32 + quad*8];
            bf16x8 b0 = *(const bf16x8*)&Vts[wn*32 +      l16][s*32 + quad*8];
            bf16x8 b1 = *(const bf16x8*)&Vts[wn*32 + 16 + l16][s*32 + quad*8];
            y[0][0] = __builtin_amdgcn_mfma_f32_16x16x32_bf16(a0, b0, y[0][0], 0,0,0);
            y[0][1] = __builtin_amdgcn_mfma_f32_16x16x32_bf16(a0, b1, y[0][1], 0,0,0);
            y[1][0] = __builtin_amdgcn_mfma_f32_16x16x32_bf16(a1, b0, y[1][0], 0,0,0);
            y[1][1] = __builtin_amdgcn_mfma_f32_16x16x32_bf16(a1, b1, y[1][1], 0,0,0);
        }
        __syncthreads();  // protect Ksh/Vts/Ss before next iteration's stores
    }

    const float g = gate[0];
    if (axis == 0) {
        #pragma unroll
        for (int ti = 0; ti < 2; ++ti)
            #pragma unroll
            for (int tj = 0; tj < 2; ++tj) {
                const int d = wn*32 + tj*16 + l16;           // = h
                #pragma unroll
                for (int r = 0; r < 4; ++r) {
                    const int tl = wm*32 + ti*16 + quad*4 + r;  // = c (w fixed = mb)
                    atomicAdd(&dst[(((size_t)b*64 + d)*64 + mb)*64 + tl], g * y[ti][tj][r]);
                }
            }
    } else {
        #pragma unroll
        for (int ti = 0; ti < 2; ++ti)
            #pragma unroll
            for (int tj = 0; tj < 2; ++tj) {
                const int d = wn*32 + tj*16 + l16;           // = w
                const float pv = p[(b*64 + mb)*64 + d] * g;  // h fixed = mb
                #pragma unroll
                for (int r = 0; r < 4; ++r) {
                    const int tl = wm*32 + ti*16 + quad*4 + r;  // = c
                    atomicAdd(&dst[(((size_t)b*64 + mb)*64 + d)*64 + tl], pv * y[ti][tj][r]);
                }
            }
    }
}

// p[pix] = conv_b + sum_nc (1 - sigmoid(predict[pix][nc])) * conv_w[nc]
__global__ __launch_bounds__(256) void pred_kernel(
    const float* __restrict__ predict, const float* __restrict__ conv_w,
    const float* __restrict__ conv_b, float* __restrict__ p)
{
    const int pix = blockIdx.x * 256 + threadIdx.x;   // 16384 pixels
    const float* row = predict + (size_t)pix * 19;
    float s = conv_b[0];
    #pragma unroll
    for (int i = 0; i < 19; ++i) {
        float sg = 1.0f / (1.0f + __expf(-row[i]));
        s += (1.0f - sg) * conv_w[i];
    }
    p[pix] = s;
}

// out = p * (feature + x1); attn width then adds p*w_gate*Yw
__global__ __launch_bounds__(256) void prefill_kernel(
    const float* __restrict__ feature, const float* __restrict__ x1,
    const float* __restrict__ p, float* __restrict__ out)
{
    const int i4 = blockIdx.x * 256 + threadIdx.x;    // 262144 float4s
    float4 f = ((const float4*)feature)[i4];
    float4 x = ((const float4*)x1)[i4];
    const float pv = p[i4 >> 4];                      // 64 floats per pixel
    float4 o;
    o.x = pv * (f.x + x.x);
    o.y = pv * (f.y + x.y);
    o.z = pv * (f.z + x.z);
    o.w = pv * (f.w + x.w);
    ((float4*)out)[i4] = o;
}

extern "C" void kernel_launch(void* const* d_in, const int* in_sizes, int n_in,
                              void* d_out, int out_size, void* d_ws, size_t ws_size,
                              hipStream_t stream) {
    const float* feature = (const float*)d_in[0];
    const float* predict = (const float*)d_in[1];
    const float* hq_w = (const float*)d_in[2];
    const float* hq_b = (const float*)d_in[3];
    const float* hv_w = (const float*)d_in[4];
    const float* hv_b = (const float*)d_in[5];
    const float* wq_w = (const float*)d_in[6];
    const float* wq_b = (const float*)d_in[7];
    const float* wv_w = (const float*)d_in[8];
    const float* wv_b = (const float*)d_in[9];
    const float* h_gate = (const float*)d_in[10];
    const float* w_gate = (const float*)d_in[11];
    const float* conv_w = (const float*)d_in[12];
    const float* conv_b = (const float*)d_in[13];
    float* out = (float*)d_out;

    // workspace layout (8.06 MiB total)
    char* ws = (char*)d_ws;
    unsigned short* Qg  = (unsigned short*)(ws);                    // 2 MiB
    unsigned short* Vtg = (unsigned short*)(ws + (2u << 20));       // 2 MiB
    float*          x1  = (float*)(ws + (4u << 20));                // 4 MiB
    float*          p   = (float*)(ws + (8u << 20));                // 64 KiB

    dim3 blk(256);
    // height stage: Q/V from feature; also x1 = feature
    prep_kernel<<<dim3(64, 4), blk, 0, stream>>>(feature, hq_w, hq_b, hv_w, hv_b,
                                                 Qg, Vtg, x1, 4096, 64);
    // x1 += h_gate * Yh
    attn_kernel<<<dim3(64, 4, 2), blk, 0, stream>>>(Qg, Vtg, h_gate, x1, nullptr, 0);
    // gate map
    pred_kernel<<<dim3(64), blk, 0, stream>>>(predict, conv_w, conv_b, p);
    // width stage: Q/V from x1
    prep_kernel<<<dim3(64, 4), blk, 0, stream>>>(x1, wq_w, wq_b, wv_w, wv_b,
                                                 Qg, Vtg, nullptr, 64, 4096);
    // out = p * (feature + x1)
    prefill_kernel<<<dim3(1024), blk, 0, stream>>>(feature, x1, p, out);
    // out += p * w_gate * Yw
    attn_kernel<<<dim3(64, 4, 2), blk, 0, stream>>>(Qg, Vtg, w_gate, out, p, 1);
}

// Round 2
// 262.763 us; speedup vs baseline: 1.0108x; 1.0108x over previous
//
#include <hip/hip_runtime.h>

// bf16 MFMA fragment types (per guide §3)
typedef short bf16x8 __attribute__((ext_vector_type(8)));
typedef float f32x4  __attribute__((ext_vector_type(4)));

#define LDP 72  // padded bf16 LDS row (64 + 8 shorts): row stride 144B, 16B-aligned

__device__ __forceinline__ unsigned short f2bf(float f) {
    union { float f; unsigned int u; } v; v.f = f;
    unsigned int r = v.u + 0x7fffu + ((v.u >> 16) & 1u);  // RNE, inputs never NaN
    return (unsigned short)(r >> 16);
}

__device__ __forceinline__ unsigned int pack_bf16(float a, float b) {
#if __has_builtin(__builtin_amdgcn_cvt_pk_bf16_f32)
    typedef __bf16 bf16x2 __attribute__((ext_vector_type(2)));
    bf16x2 p = __builtin_amdgcn_cvt_pk_bf16_f32(a, b);
    union { bf16x2 v; unsigned int u; } c; c.v = p;
    return c.u;
#else
    return (unsigned int)f2bf(a) | ((unsigned int)f2bf(b) << 16);
#endif
}

__device__ __forceinline__ float fast_sigmoid8(float x) {
    // sigmoid(x/8) with hw exp + hw rcp (1ulp rcp fine at 2% threshold)
    float e = __expf(-0.125f * x);
    return __builtin_amdgcn_rcpf(1.0f + e);
}

// ---------------------------------------------------------------------------
// prep: per (b, fixedIdx) block: slab[k][c] = src[b, ...], compute
//   Q[n=bx*64+c][j] -> Qg  [b][4096][64] bf16 (row-major)
//   V[n][j]         -> Vtg [b][64][4096] bf16 (transposed)
// height stage: bx=w, k=h (sK=4096,sF=64); width stage: bx=h, k=w (sK=64,sF=4096)
// ---------------------------------------------------------------------------
__global__ __launch_bounds__(256) void prep_kernel(
    const float* __restrict__ src,
    const float* __restrict__ wq, const float* __restrict__ bq,
    const float* __restrict__ wv, const float* __restrict__ bv,
    unsigned short* __restrict__ Qg, unsigned short* __restrict__ Vtg,
    float* __restrict__ x1out, int sK, int sF)
{
    __shared__ float slab[64][65];
    __shared__ float wqs[4096];
    __shared__ float wvs[4096];

    const int t  = threadIdx.x;
    const int bx = blockIdx.x, b = blockIdx.y;

    {   // stage weights
        const float4* wq4 = (const float4*)wq;
        const float4* wv4 = (const float4*)wv;
        float4* q4 = (float4*)wqs; float4* v4 = (float4*)wvs;
        #pragma unroll
        for (int i = 0; i < 4; ++i) {
            q4[i*256 + t] = wq4[i*256 + t];
            v4[i*256 + t] = wv4[i*256 + t];
        }
    }
    {   // stage slab
        const int k = t >> 2, c0 = (t & 3) << 4;
        const size_t sb = (size_t)b*262144 + (size_t)k*sK + (size_t)bx*sF + c0;
        #pragma unroll
        for (int i = 0; i < 4; ++i) {
            float4 v = *(const float4*)&src[sb + i*4];
            *(float4*)&slab[k][c0 + i*4] = v;
            if (x1out) *(float4*)&x1out[sb + i*4] = v;
        }
    }
    __syncthreads();

    const int c = t & 63, jg = t >> 6;
    float qa[16], va[16];
    #pragma unroll
    for (int jj = 0; jj < 16; ++jj) { qa[jj] = bq[jg*16+jj]; va[jj] = bv[jg*16+jj]; }
    for (int k = 0; k < 64; ++k) {
        const float xv = slab[k][c];
        const float* wqr = &wqs[k*64 + jg*16];
        const float* wvr = &wvs[k*64 + jg*16];
        #pragma unroll
        for (int jj = 0; jj < 16; ++jj) {
            qa[jj] += xv * wqr[jj];
            va[jj] += xv * wvr[jj];
        }
    }
    const int token = bx*64 + c;
    union { unsigned short s[16]; uint4 v[2]; } qp, vp;
    #pragma unroll
    for (int jj = 0; jj < 16; ++jj) { qp.s[jj] = f2bf(qa[jj]); vp.s[jj] = f2bf(va[jj]); }
    const size_t qoff = ((size_t)b*4096 + token)*64 + jg*16;
    *(uint4*)&Qg[qoff]     = qp.v[0];
    *(uint4*)&Qg[qoff + 8] = qp.v[1];
    #pragma unroll
    for (int jj = 0; jj < 16; ++jj)
        Vtg[((size_t)b*64 + jg*16 + jj)*4096 + token] = vp.s[jj];
}

// ---------------------------------------------------------------------------
// attn v2: Y[n][d] = sum_m sigmoid(Q[n]·Q[m]/8) V[m][d].
// Each block: 64-query tile (mb), key-range split over gridDim.z=4 (16 kb iters).
// Wave w owns query-16-block m=w (rows w*16..+16) for ALL keys/d.
// Score tile computed TRANSPOSED: T_u = K_u · Q^T (MFMA A=K rows, B=Q rows), so
// C-layout lane holds (key=u*16+quad*4+r, query=w*16+l16): 4 CONSECUTIVE keys
// -> sigmoid + packed b32 stores into row-major Ss[query][key].
// Ss rows are wave-private (w*16..+16): write->read needs no barrier (lgkmcnt).
// 2 barriers per iter. Epilogue: atomicAdd partial Y into dst.
// ---------------------------------------------------------------------------
__global__ __launch_bounds__(256) void attn_kernel(
    const unsigned short* __restrict__ Qg,
    const unsigned short* __restrict__ Vtg,
    const float* __restrict__ gate,
    float* __restrict__ dst,
    const float* __restrict__ p,
    int axis)
{
    __shared__ unsigned short Ksh[64][LDP];
    __shared__ unsigned short Vts[64][LDP];
    __shared__ unsigned int   Ss [64][LDP/2];   // bf16 pairs, same 144B row stride

    const int t = threadIdx.x;
    const int mb = blockIdx.x, b = blockIdx.y, ksplit = blockIdx.z;
    const int lane = t & 63, w = t >> 6;
    const int quad = lane >> 4, l16 = lane & 15;

    const unsigned short* Qbase = Qg  + (size_t)b*262144;
    const unsigned short* Vbase = Vtg + (size_t)b*262144;

    // hoisted Q B-frags, direct from global: B[k=d=s*32+quad*8+j][n=query=l16]
    bf16x8 qb[2];
    {
        const unsigned short* qrow = Qbase + (size_t)(mb*64 + w*16 + l16)*64;
        qb[0] = *(const bf16x8*)&qrow[quad*8];
        qb[1] = *(const bf16x8*)&qrow[32 + quad*8];
    }

    f32x4 y[4];
    #pragma unroll
    for (int db = 0; db < 4; ++db) y[db] = (f32x4){0.f, 0.f, 0.f, 0.f};

    const int lrow = t >> 2, loff = (t & 3) << 4;
    const unsigned short* SsS = (const unsigned short*)&Ss[0][0];

    for (int kb = 0; kb < 16; ++kb) {
        const int key0 = ksplit*1024 + kb*64;
        {   // stage K tile (rows of Q) and Vt tile
            const uint4* gk = (const uint4*)(Qbase + (size_t)(key0 + lrow)*64 + loff);
            uint4 k0 = gk[0], k1 = gk[1];
            const uint4* gv = (const uint4*)(Vbase + (size_t)lrow*4096 + key0 + loff);
            uint4 v0 = gv[0], v1 = gv[1];
            *(uint4*)&Ksh[lrow][loff]     = k0;
            *(uint4*)&Ksh[lrow][loff + 8] = k1;
            *(uint4*)&Vts[lrow][loff]     = v0;
            *(uint4*)&Vts[lrow][loff + 8] = v1;
        }
        __syncthreads();

        // T_u = K_u · Q_w^T   (A = K rows, B = Q rows) ; accumulate over d (s=0,1)
        f32x4 tacc[4];
        #pragma unroll
        for (int u = 0; u < 4; ++u) tacc[u] = (f32x4){0.f, 0.f, 0.f, 0.f};
        #pragma unroll
        for (int s = 0; s < 2; ++s) {
            #pragma unroll
            for (int u = 0; u < 4; ++u) {
                bf16x8 ka = *(const bf16x8*)&Ksh[u*16 + l16][s*32 + quad*8];
                tacc[u] = __builtin_amdgcn_mfma_f32_16x16x32_bf16(ka, qb[s], tacc[u], 0,0,0);
            }
        }
        // lane holds S[query=w*16+l16][key=u*16+quad*4+r], r=0..3 -> sigmoid, pack, store
        const int srow = w*16 + l16;
        #pragma unroll
        for (int u = 0; u < 4; ++u) {
            float s0 = fast_sigmoid8(tacc[u][0]);
            float s1 = fast_sigmoid8(tacc[u][1]);
            float s2 = fast_sigmoid8(tacc[u][2]);
            float s3 = fast_sigmoid8(tacc[u][3]);
            Ss[srow][u*8 + quad*2 + 0] = pack_bf16(s0, s1);
            Ss[srow][u*8 + quad*2 + 1] = pack_bf16(s2, s3);
        }
        // no barrier: Ss rows are wave-private; lgkmcnt orders write->read in-wave

        // Y += S·V : A = S[m=query=l16][k=key], B[k=key][n=d] from Vt rows
        #pragma unroll
        for (int s = 0; s < 2; ++s) {
            bf16x8 sa = *(const bf16x8*)&SsS[(size_t)(w*16 + l16)*LDP + s*32 + quad*8];
            #pragma unroll
            for (int db = 0; db < 4; ++db) {
                bf16x8 vb = *(const bf16x8*)&Vts[db*16 + l16][s*32 + quad*8];
                y[db] = __builtin_amdgcn_mfma_f32_16x16x32_bf16(sa, vb, y[db], 0,0,0);
            }
        }
        __syncthreads();  // protect Ksh/Vts before next iteration's staging
    }

    const float g = gate[0];
    if (axis == 0) {
        #pragma unroll
        for (int db = 0; db < 4; ++db) {
            const int d = db*16 + l16;                      // = h
            #pragma unroll
            for (int r = 0; r < 4; ++r) {
                const int tl = w*16 + quad*4 + r;           // = c (w-coord fixed = mb)
                atomicAdd(&dst[(((size_t)b*64 + d)*64 + mb)*64 + tl], g * y[db][r]);
            }
        }
    } else {
        #pragma unroll
        for (int db = 0; db < 4; ++db) {
            const int d = db*16 + l16;                      // = w-coord
            const float pv = p[(b*64 + mb)*64 + d] * g;     // h fixed = mb
            #pragma unroll
            for (int r = 0; r < 4; ++r) {
                const int tl = w*16 + quad*4 + r;           // = c
                atomicAdd(&dst[(((size_t)b*64 + mb)*64 + d)*64 + tl], pv * y[db][r]);
            }
        }
    }
}

// p[pix] = conv_b + sum_nc (1 - sigmoid(predict[pix][nc])) * conv_w[nc]
__global__ __launch_bounds__(256) void pred_kernel(
    const float* __restrict__ predict, const float* __restrict__ conv_w,
    const float* __restrict__ conv_b, float* __restrict__ p)
{
    const int pix = blockIdx.x * 256 + threadIdx.x;   // 16384 pixels
    const float* row = predict + (size_t)pix * 19;
    float s = conv_b[0];
    #pragma unroll
    for (int i = 0; i < 19; ++i) {
        float sg = 1.0f / (1.0f + __expf(-row[i]));
        s += (1.0f - sg) * conv_w[i];
    }
    p[pix] = s;
}

// out = p * (feature + x1); attn width stage then adds p*w_gate*Yw
__global__ __launch_bounds__(256) void prefill_kernel(
    const float* __restrict__ feature, const float* __restrict__ x1,
    const float* __restrict__ p, float* __restrict__ out)
{
    const int i4 = blockIdx.x * 256 + threadIdx.x;    // 262144 float4s
    float4 f = ((const float4*)feature)[i4];
    float4 x = ((const float4*)x1)[i4];
    const float pv = p[i4 >> 4];                      // 64 floats per pixel
    float4 o;
    o.x = pv * (f.x + x.x);
    o.y = pv * (f.y + x.y);
    o.z = pv * (f.z + x.z);
    o.w = pv * (f.w + x.w);
    ((float4*)out)[i4] = o;
}

extern "C" void kernel_launch(void* const* d_in, const int* in_sizes, int n_in,
                              void* d_out, int out_size, void* d_ws, size_t ws_size,
                              hipStream_t stream) {
    const float* feature = (const float*)d_in[0];
    const float* predict = (const float*)d_in[1];
    const float* hq_w = (const float*)d_in[2];
    const float* hq_b = (const float*)d_in[3];
    const float* hv_w = (const float*)d_in[4];
    const float* hv_b = (const float*)d_in[5];
    const float* wq_w = (const float*)d_in[6];
    const float* wq_b = (const float*)d_in[7];
    const float* wv_w = (const float*)d_in[8];
    const float* wv_b = (const float*)d_in[9];
    const float* h_gate = (const float*)d_in[10];
    const float* w_gate = (const float*)d_in[11];
    const float* conv_w = (const float*)d_in[12];
    const float* conv_b = (const float*)d_in[13];
    float* out = (float*)d_out;

    // workspace layout (8.06 MiB total)
    char* ws = (char*)d_ws;
    unsigned short* Qg  = (unsigned short*)(ws);                    // 2 MiB
    unsigned short* Vtg = (unsigned short*)(ws + (2u << 20));       // 2 MiB
    float*          x1  = (float*)(ws + (4u << 20));                // 4 MiB
    float*          p   = (float*)(ws + (8u << 20));                // 64 KiB

    dim3 blk(256);
    // height stage: Q/V from feature; also x1 = feature
    prep_kernel<<<dim3(64, 4), blk, 0, stream>>>(feature, hq_w, hq_b, hv_w, hv_b,
                                                 Qg, Vtg, x1, 4096, 64);
    // x1 += h_gate * Yh
    attn_kernel<<<dim3(64, 4, 4), blk, 0, stream>>>(Qg, Vtg, h_gate, x1, nullptr, 0);
    // gate map
    pred_kernel<<<dim3(64), blk, 0, stream>>>(predict, conv_w, conv_b, p);
    // width stage: Q/V from x1
    prep_kernel<<<dim3(64, 4), blk, 0, stream>>>(x1, wq_w, wq_b, wv_w, wv_b,
                                                 Qg, Vtg, nullptr, 64, 4096);
    // out = p * (feature + x1)
    prefill_kernel<<<dim3(1024), blk, 0, stream>>>(feature, x1, p, out);
    // out += p * w_gate * Yw
    attn_kernel<<<dim3(64, 4, 4), blk, 0, stream>>>(Qg, Vtg, w_gate, out, p, 1);
}

// Round 3
// 252.282 us; speedup vs baseline: 1.0528x; 1.0415x over previous
//
#include <hip/hip_runtime.h>

// bf16 MFMA fragment types (per guide §3)
typedef short bf16x8 __attribute__((ext_vector_type(8)));
typedef float f32x4  __attribute__((ext_vector_type(4)));

#define LDP 72  // padded bf16 LDS row (64 + 8 shorts): row stride 144B, 16B-aligned

__device__ __forceinline__ unsigned short f2bf(float f) {
    union { float f; unsigned int u; } v; v.f = f;
    unsigned int r = v.u + 0x7fffu + ((v.u >> 16) & 1u);  // RNE, inputs never NaN
    return (unsigned short)(r >> 16);
}

__device__ __forceinline__ unsigned int pack_bf16(float a, float b) {
#if __has_builtin(__builtin_amdgcn_cvt_pk_bf16_f32)
    typedef __bf16 bf16x2 __attribute__((ext_vector_type(2)));
    bf16x2 p = __builtin_amdgcn_cvt_pk_bf16_f32(a, b);
    union { bf16x2 v; unsigned int u; } c; c.v = p;
    return c.u;
#else
    return (unsigned int)f2bf(a) | ((unsigned int)f2bf(b) << 16);
#endif
}

__device__ __forceinline__ float fast_sigmoid8(float x) {
    float e = __expf(-0.125f * x);
    return __builtin_amdgcn_rcpf(1.0f + e);
}

// ---------------------------------------------------------------------------
// prep: per (b, fixedIdx) block: slab[k][c] = src[b, ...], compute
//   Q[n=bx*64+c][j] -> Qg  [b][4096][64] bf16 (row-major)
//   V[n][j]         -> Vtg [b][64][4096] bf16 (transposed)
// height stage: bx=w, k=h (sK=4096,sF=64); width stage: bx=h, k=w (sK=64,sF=4096)
// ---------------------------------------------------------------------------
__global__ __launch_bounds__(256) void prep_kernel(
    const float* __restrict__ src,
    const float* __restrict__ wq, const float* __restrict__ bq,
    const float* __restrict__ wv, const float* __restrict__ bv,
    unsigned short* __restrict__ Qg, unsigned short* __restrict__ Vtg,
    float* __restrict__ x1out, int sK, int sF)
{
    __shared__ float slab[64][65];
    __shared__ float wqs[4096];
    __shared__ float wvs[4096];

    const int t  = threadIdx.x;
    const int bx = blockIdx.x, b = blockIdx.y;

    {   // stage weights
        const float4* wq4 = (const float4*)wq;
        const float4* wv4 = (const float4*)wv;
        float4* q4 = (float4*)wqs; float4* v4 = (float4*)wvs;
        #pragma unroll
        for (int i = 0; i < 4; ++i) {
            q4[i*256 + t] = wq4[i*256 + t];
            v4[i*256 + t] = wv4[i*256 + t];
        }
    }
    {   // stage slab
        const int k = t >> 2, c0 = (t & 3) << 4;
        const size_t sb = (size_t)b*262144 + (size_t)k*sK + (size_t)bx*sF + c0;
        #pragma unroll
        for (int i = 0; i < 4; ++i) {
            float4 v = *(const float4*)&src[sb + i*4];
            *(float4*)&slab[k][c0 + i*4] = v;
            if (x1out) *(float4*)&x1out[sb + i*4] = v;
        }
    }
    __syncthreads();

    const int c = t & 63, jg = t >> 6;
    float qa[16], va[16];
    #pragma unroll
    for (int jj = 0; jj < 16; ++jj) { qa[jj] = bq[jg*16+jj]; va[jj] = bv[jg*16+jj]; }
    for (int k = 0; k < 64; ++k) {
        const float xv = slab[k][c];
        const float* wqr = &wqs[k*64 + jg*16];
        const float* wvr = &wvs[k*64 + jg*16];
        #pragma unroll
        for (int jj = 0; jj < 16; ++jj) {
            qa[jj] += xv * wqr[jj];
            va[jj] += xv * wvr[jj];
        }
    }
    const int token = bx*64 + c;
    union { unsigned short s[16]; uint4 v[2]; } qp, vp;
    #pragma unroll
    for (int jj = 0; jj < 16; ++jj) { qp.s[jj] = f2bf(qa[jj]); vp.s[jj] = f2bf(va[jj]); }
    const size_t qoff = ((size_t)b*4096 + token)*64 + jg*16;
    *(uint4*)&Qg[qoff]     = qp.v[0];
    *(uint4*)&Qg[qoff + 8] = qp.v[1];
    #pragma unroll
    for (int jj = 0; jj < 16; ++jj)
        Vtg[((size_t)b*64 + jg*16 + jj)*4096 + token] = vp.s[jj];
}

// ---------------------------------------------------------------------------
// attn v3: software-pipelined. LDS ping-pong for K/Vt tiles; iteration k
// prefetches tile k+1 into registers at the top (loads in flight across the
// whole compute phase), writes them to the idle buffer at the bottom, ONE
// barrier per iteration. Score tile computed transposed (T = K·Q^T) so each
// lane holds 4 consecutive keys for one query -> packed b64 store into
// wave-private Ss rows (no barrier between S write and S·V read).
// ---------------------------------------------------------------------------
__global__ __launch_bounds__(256) void attn_kernel(
    const unsigned short* __restrict__ Qg,
    const unsigned short* __restrict__ Vtg,
    const float* __restrict__ gate,
    float* __restrict__ dst,
    const float* __restrict__ p,
    int axis)
{
    __shared__ unsigned short Ksh[2][64][LDP];
    __shared__ unsigned short Vts[2][64][LDP];
    __shared__ unsigned int   Ss [64][LDP/2];   // bf16 pairs, 144B row stride

    const int t = threadIdx.x;
    const int mb = blockIdx.x, b = blockIdx.y, ksplit = blockIdx.z;
    const int lane = t & 63, w = t >> 6;
    const int quad = lane >> 4, l16 = lane & 15;

    const unsigned short* Qbase = Qg  + (size_t)b*262144;
    const unsigned short* Vbase = Vtg + (size_t)b*262144;

    // hoisted Q B-frags, direct from global: B[k=d=s*32+quad*8+j][n=query=l16]
    bf16x8 qb[2];
    {
        const unsigned short* qrow = Qbase + (size_t)(mb*64 + w*16 + l16)*64;
        qb[0] = *(const bf16x8*)&qrow[quad*8];
        qb[1] = *(const bf16x8*)&qrow[32 + quad*8];
    }

    f32x4 y[4];
    #pragma unroll
    for (int db = 0; db < 4; ++db) y[db] = (f32x4){0.f, 0.f, 0.f, 0.f};

    const int lrow = t >> 2, loff = (t & 3) << 4;
    const unsigned short* SsS = (const unsigned short*)&Ss[0][0];

    {   // prologue: stage tile 0 into buffer 0
        const int key0 = ksplit*1024;
        const uint4* gk = (const uint4*)(Qbase + (size_t)(key0 + lrow)*64 + loff);
        uint4 k0 = gk[0], k1 = gk[1];
        const uint4* gv = (const uint4*)(Vbase + (size_t)lrow*4096 + key0 + loff);
        uint4 v0 = gv[0], v1 = gv[1];
        *(uint4*)&Ksh[0][lrow][loff]     = k0;
        *(uint4*)&Ksh[0][lrow][loff + 8] = k1;
        *(uint4*)&Vts[0][lrow][loff]     = v0;
        *(uint4*)&Vts[0][lrow][loff + 8] = v1;
    }
    __syncthreads();

    for (int kb = 0; kb < 16; ++kb) {
        const int cur = kb & 1, nxt = cur ^ 1;

        // prefetch tile kb+1 (loads stay in flight across the compute phase)
        uint4 nk0 = {}, nk1 = {}, nv0 = {}, nv1 = {};
        if (kb < 15) {
            const int keyn = ksplit*1024 + (kb+1)*64;
            const uint4* gk = (const uint4*)(Qbase + (size_t)(keyn + lrow)*64 + loff);
            nk0 = gk[0]; nk1 = gk[1];
            const uint4* gv = (const uint4*)(Vbase + (size_t)lrow*4096 + keyn + loff);
            nv0 = gv[0]; nv1 = gv[1];
        }

        // T_u = K_u · Q_w^T   (A = K rows, B = Q rows); accumulate over d (s=0,1)
        f32x4 tacc[4];
        #pragma unroll
        for (int u = 0; u < 4; ++u) tacc[u] = (f32x4){0.f, 0.f, 0.f, 0.f};
        #pragma unroll
        for (int s = 0; s < 2; ++s) {
            #pragma unroll
            for (int u = 0; u < 4; ++u) {
                bf16x8 ka = *(const bf16x8*)&Ksh[cur][u*16 + l16][s*32 + quad*8];
                tacc[u] = __builtin_amdgcn_mfma_f32_16x16x32_bf16(ka, qb[s], tacc[u], 0,0,0);
            }
        }
        // lane holds S[query=w*16+l16][key=u*16+quad*4+r] -> sigmoid, pack, b64 store
        const int srow = w*16 + l16;
        #pragma unroll
        for (int u = 0; u < 4; ++u) {
            uint2 pk;
            pk.x = pack_bf16(fast_sigmoid8(tacc[u][0]), fast_sigmoid8(tacc[u][1]));
            pk.y = pack_bf16(fast_sigmoid8(tacc[u][2]), fast_sigmoid8(tacc[u][3]));
            *(uint2*)&Ss[srow][u*8 + quad*2] = pk;
        }
        // no barrier: Ss rows are wave-private; lgkmcnt orders write->read in-wave

        // Y += S·V : A = S[m=query=l16][k=key], B[k=key][n=d] from Vt rows
        #pragma unroll
        for (int s = 0; s < 2; ++s) {
            bf16x8 sa = *(const bf16x8*)&SsS[(size_t)(w*16 + l16)*LDP + s*32 + quad*8];
            #pragma unroll
            for (int db = 0; db < 4; ++db) {
                bf16x8 vb = *(const bf16x8*)&Vts[cur][db*16 + l16][s*32 + quad*8];
                y[db] = __builtin_amdgcn_mfma_f32_16x16x32_bf16(sa, vb, y[db], 0,0,0);
            }
        }

        // drain prefetch into the idle buffer (nobody reads nxt this iteration)
        if (kb < 15) {
            *(uint4*)&Ksh[nxt][lrow][loff]     = nk0;
            *(uint4*)&Ksh[nxt][lrow][loff + 8] = nk1;
            *(uint4*)&Vts[nxt][lrow][loff]     = nv0;
            *(uint4*)&Vts[nxt][lrow][loff + 8] = nv1;
        }
        __syncthreads();   // single barrier per iteration
    }

    const float g = gate[0];
    if (axis == 0) {
        #pragma unroll
        for (int db = 0; db < 4; ++db) {
            const int d = db*16 + l16;                      // = h
            #pragma unroll
            for (int r = 0; r < 4; ++r) {
                const int tl = w*16 + quad*4 + r;           // = c (w-coord fixed = mb)
                atomicAdd(&dst[(((size_t)b*64 + d)*64 + mb)*64 + tl], g * y[db][r]);
            }
        }
    } else {
        #pragma unroll
        for (int db = 0; db < 4; ++db) {
            const int d = db*16 + l16;                      // = w-coord
            const float pv = p[(b*64 + mb)*64 + d] * g;     // h fixed = mb
            #pragma unroll
            for (int r = 0; r < 4; ++r) {
                const int tl = w*16 + quad*4 + r;           // = c
                atomicAdd(&dst[(((size_t)b*64 + mb)*64 + d)*64 + tl], pv * y[db][r]);
            }
        }
    }
}

// p[pix] = conv_b + sum_nc (1 - sigmoid(predict[pix][nc])) * conv_w[nc]
__global__ __launch_bounds__(256) void pred_kernel(
    const float* __restrict__ predict, const float* __restrict__ conv_w,
    const float* __restrict__ conv_b, float* __restrict__ p)
{
    const int pix = blockIdx.x * 256 + threadIdx.x;   // 16384 pixels
    const float* row = predict + (size_t)pix * 19;
    float s = conv_b[0];
    #pragma unroll
    for (int i = 0; i < 19; ++i) {
        float sg = 1.0f / (1.0f + __expf(-row[i]));
        s += (1.0f - sg) * conv_w[i];
    }
    p[pix] = s;
}

// out = p * (feature + x1); attn width stage then adds p*w_gate*Yw
__global__ __launch_bounds__(256) void prefill_kernel(
    const float* __restrict__ feature, const float* __restrict__ x1,
    const float* __restrict__ p, float* __restrict__ out)
{
    const int i4 = blockIdx.x * 256 + threadIdx.x;    // 262144 float4s
    float4 f = ((const float4*)feature)[i4];
    float4 x = ((const float4*)x1)[i4];
    const float pv = p[i4 >> 4];                      // 64 floats per pixel
    float4 o;
    o.x = pv * (f.x + x.x);
    o.y = pv * (f.y + x.y);
    o.z = pv * (f.z + x.z);
    o.w = pv * (f.w + x.w);
    ((float4*)out)[i4] = o;
}

extern "C" void kernel_launch(void* const* d_in, const int* in_sizes, int n_in,
                              void* d_out, int out_size, void* d_ws, size_t ws_size,
                              hipStream_t stream) {
    const float* feature = (const float*)d_in[0];
    const float* predict = (const float*)d_in[1];
    const float* hq_w = (const float*)d_in[2];
    const float* hq_b = (const float*)d_in[3];
    const float* hv_w = (const float*)d_in[4];
    const float* hv_b = (const float*)d_in[5];
    const float* wq_w = (const float*)d_in[6];
    const float* wq_b = (const float*)d_in[7];
    const float* wv_w = (const float*)d_in[8];
    const float* wv_b = (const float*)d_in[9];
    const float* h_gate = (const float*)d_in[10];
    const float* w_gate = (const float*)d_in[11];
    const float* conv_w = (const float*)d_in[12];
    const float* conv_b = (const float*)d_in[13];
    float* out = (float*)d_out;

    // workspace layout (8.06 MiB total)
    char* ws = (char*)d_ws;
    unsigned short* Qg  = (unsigned short*)(ws);                    // 2 MiB
    unsigned short* Vtg = (unsigned short*)(ws + (2u << 20));       // 2 MiB
    float*          x1  = (float*)(ws + (4u << 20));                // 4 MiB
    float*          p   = (float*)(ws + (8u << 20));                // 64 KiB

    dim3 blk(256);
    // height stage: Q/V from feature; also x1 = feature
    prep_kernel<<<dim3(64, 4), blk, 0, stream>>>(feature, hq_w, hq_b, hv_w, hv_b,
                                                 Qg, Vtg, x1, 4096, 64);
    // x1 += h_gate * Yh
    attn_kernel<<<dim3(64, 4, 4), blk, 0, stream>>>(Qg, Vtg, h_gate, x1, nullptr, 0);
    // gate map
    pred_kernel<<<dim3(64), blk, 0, stream>>>(predict, conv_w, conv_b, p);
    // width stage: Q/V from x1
    prep_kernel<<<dim3(64, 4), blk, 0, stream>>>(x1, wq_w, wq_b, wv_w, wv_b,
                                                 Qg, Vtg, nullptr, 64, 4096);
    // out = p * (feature + x1)
    prefill_kernel<<<dim3(1024), blk, 0, stream>>>(feature, x1, p, out);
    // out += p * w_gate * Yw
    attn_kernel<<<dim3(64, 4, 4), blk, 0, stream>>>(Qg, Vtg, w_gate, out, p, 1);
}